// Round 6
// baseline (390.838 us; speedup 1.0000x reference)
//
#include <hip/hip_runtime.h>

typedef float vf2  __attribute__((ext_vector_type(2)));
typedef float v128f __attribute__((ext_vector_type(128)));

__device__ __forceinline__ vf2 cmulv(vf2 a, vf2 b){
  vf2 br; br.x = -b.y; br.y = b.x;
  return a.x*b + a.y*br;
}

#define ROWS 66   // 32-row transpose buffer, 66 float2/row (64 + 2 pad -> bank stagger)
#define FENCE() asm volatile("" ::: "memory")

// merged-diagonal angle for wire j of diagonal d (wave-uniform); d, j compile-time
#define ALPHA(d, j, XR) (((d) & 1) \
  ? (W[((((d)>>1)*2+1)*12+(j))*3+0] + W[((((d)>>1)*2+0)*12+(j))*3+2]) \
  : (W[((((d)>>1)*2+0)*12+(j))*3+0] + XR[(j)] + W[(((((d)>>1)-1)*2+1)*12+(j))*3+2]))

// tan-form butterfly (deferred cosine), 4 FMA
#define BFLY(ST, w0i, w1i, t_) do{ \
  const float ax_=ST[2*(w0i)], ay_=ST[2*(w0i)+1]; \
  const float bx_=ST[2*(w1i)], by_=ST[2*(w1i)+1]; \
  ST[2*(w0i)]   = __builtin_fmaf(-(t_), bx_, ax_); \
  ST[2*(w0i)+1] = __builtin_fmaf(-(t_), by_, ay_); \
  ST[2*(w1i)]   = __builtin_fmaf( (t_), ax_, bx_); \
  ST[2*(w1i)+1] = __builtin_fmaf( (t_), ay_, by_); \
}while(0)

// 6 RY gates, single state
#define GATES6_1(ST, sl, par) do{ \
  _Pragma("unroll") \
  for (int lb = 0; lb < 6; lb++){ \
    const int wire_ = (par) ? (5 - lb) : (11 - lb); \
    const float t_ = scsl[(sl)*12 + wire_].y; \
    _Pragma("unroll") \
    for (int w0 = 0; w0 < 64; w0++){ \
      if (w0 & (1 << lb)) continue; \
      const int w1 = w0 | (1 << lb); \
      BFLY(ST, w0, w1, t_); \
    } \
  } \
}while(0)

// 6 RY gates, BOTH states interleaved (two independent dep chains fill stalls);
// gate angles are weight-only -> t_ shared by both samples
#define GATES6_2(sl, par) do{ \
  _Pragma("unroll") \
  for (int lb = 0; lb < 6; lb++){ \
    const int wire_ = (par) ? (5 - lb) : (11 - lb); \
    const float t_ = scsl[(sl)*12 + wire_].y; \
    _Pragma("unroll") \
    for (int w0 = 0; w0 < 64; w0++){ \
      if (w0 & (1 << lb)) continue; \
      const int w1 = w0 | (1 << lb); \
      BFLY(stA, w0, w1, t_); \
      BFLY(stB, w0, w1, t_); \
    } \
  } \
}while(0)

// Two-phase 64x64 lane<->reg transpose through a 32-row LDS buffer (R2/R3-verified).
// Phase A: cross blocks (lanes<32 export regs 32..63 / import the half lanes>=32
// exported -> no hazard); phase B: diagonal blocks.  st[] indices compile-time.
#define TRANSPOSE_S(ST, XB) do{ \
  if (u < 32){ \
    _Pragma("unroll") \
    for (int w = 32; w < 64; w++){ vf2 t_; t_.x = ST[2*w]; t_.y = ST[2*w+1]; \
      XB[(w-32) * ROWS + u] = t_; } \
  } else { \
    _Pragma("unroll") \
    for (int w = 0; w < 32; w++){ vf2 t_; t_.x = ST[2*w]; t_.y = ST[2*w+1]; \
      XB[w * ROWS + u] = t_; } \
  } \
  FENCE(); \
  if (u < 32){ \
    _Pragma("unroll") \
    for (int t = 0; t < 16; t++){ \
      float4 f_ = ((const float4*)&XB[u * ROWS + 32])[t]; \
      ST[64+4*t] = f_.x; ST[64+4*t+1] = f_.y; ST[64+4*t+2] = f_.z; ST[64+4*t+3] = f_.w; } \
  } else { \
    _Pragma("unroll") \
    for (int t = 0; t < 16; t++){ \
      float4 f_ = ((const float4*)&XB[(u-32) * ROWS])[t]; \
      ST[4*t] = f_.x; ST[4*t+1] = f_.y; ST[4*t+2] = f_.z; ST[4*t+3] = f_.w; } \
  } \
  FENCE(); \
  if (u < 32){ \
    _Pragma("unroll") \
    for (int w = 0; w < 32; w++){ vf2 t_; t_.x = ST[2*w]; t_.y = ST[2*w+1]; \
      XB[w * ROWS + u] = t_; } \
  } else { \
    _Pragma("unroll") \
    for (int w = 32; w < 64; w++){ vf2 t_; t_.x = ST[2*w]; t_.y = ST[2*w+1]; \
      XB[(w-32) * ROWS + u] = t_; } \
  } \
  FENCE(); \
  if (u < 32){ \
    _Pragma("unroll") \
    for (int t = 0; t < 16; t++){ \
      float4 f_ = ((const float4*)&XB[u * ROWS])[t]; \
      ST[4*t] = f_.x; ST[4*t+1] = f_.y; ST[4*t+2] = f_.z; ST[4*t+3] = f_.w; } \
  } else { \
    _Pragma("unroll") \
    for (int t = 0; t < 16; t++){ \
      float4 f_ = ((const float4*)&XB[(u-32) * ROWS + 32])[t]; \
      ST[64+4*t] = f_.x; ST[64+4*t+1] = f_.y; ST[64+4*t+2] = f_.z; ST[64+4*t+3] = f_.w; } \
  } \
  FENCE(); \
}while(0)

// dual transpose: A and B through disjoint buffers, phases merged so the LDS ops of
// both samples pipeline together between fences
#define TRANSPOSE2() do{ \
  if (u < 32){ \
    _Pragma("unroll") \
    for (int w = 32; w < 64; w++){ vf2 tA_, tB_; \
      tA_.x = stA[2*w]; tA_.y = stA[2*w+1]; xbA[(w-32) * ROWS + u] = tA_; \
      tB_.x = stB[2*w]; tB_.y = stB[2*w+1]; xbB[(w-32) * ROWS + u] = tB_; } \
  } else { \
    _Pragma("unroll") \
    for (int w = 0; w < 32; w++){ vf2 tA_, tB_; \
      tA_.x = stA[2*w]; tA_.y = stA[2*w+1]; xbA[w * ROWS + u] = tA_; \
      tB_.x = stB[2*w]; tB_.y = stB[2*w+1]; xbB[w * ROWS + u] = tB_; } \
  } \
  FENCE(); \
  if (u < 32){ \
    _Pragma("unroll") \
    for (int t = 0; t < 16; t++){ \
      float4 fA_ = ((const float4*)&xbA[u * ROWS + 32])[t]; \
      float4 fB_ = ((const float4*)&xbB[u * ROWS + 32])[t]; \
      stA[64+4*t] = fA_.x; stA[64+4*t+1] = fA_.y; stA[64+4*t+2] = fA_.z; stA[64+4*t+3] = fA_.w; \
      stB[64+4*t] = fB_.x; stB[64+4*t+1] = fB_.y; stB[64+4*t+2] = fB_.z; stB[64+4*t+3] = fB_.w; } \
  } else { \
    _Pragma("unroll") \
    for (int t = 0; t < 16; t++){ \
      float4 fA_ = ((const float4*)&xbA[(u-32) * ROWS])[t]; \
      float4 fB_ = ((const float4*)&xbB[(u-32) * ROWS])[t]; \
      stA[4*t] = fA_.x; stA[4*t+1] = fA_.y; stA[4*t+2] = fA_.z; stA[4*t+3] = fA_.w; \
      stB[4*t] = fB_.x; stB[4*t+1] = fB_.y; stB[4*t+2] = fB_.z; stB[4*t+3] = fB_.w; } \
  } \
  FENCE(); \
  if (u < 32){ \
    _Pragma("unroll") \
    for (int w = 0; w < 32; w++){ vf2 tA_, tB_; \
      tA_.x = stA[2*w]; tA_.y = stA[2*w+1]; xbA[w * ROWS + u] = tA_; \
      tB_.x = stB[2*w]; tB_.y = stB[2*w+1]; xbB[w * ROWS + u] = tB_; } \
  } else { \
    _Pragma("unroll") \
    for (int w = 32; w < 64; w++){ vf2 tA_, tB_; \
      tA_.x = stA[2*w]; tA_.y = stA[2*w+1]; xbA[(w-32) * ROWS + u] = tA_; \
      tB_.x = stB[2*w]; tB_.y = stB[2*w+1]; xbB[(w-32) * ROWS + u] = tB_; } \
  } \
  FENCE(); \
  if (u < 32){ \
    _Pragma("unroll") \
    for (int t = 0; t < 16; t++){ \
      float4 fA_ = ((const float4*)&xbA[u * ROWS])[t]; \
      float4 fB_ = ((const float4*)&xbB[u * ROWS])[t]; \
      stA[4*t] = fA_.x; stA[4*t+1] = fA_.y; stA[4*t+2] = fA_.z; stA[4*t+3] = fA_.w; \
      stB[4*t] = fB_.x; stB[4*t+1] = fB_.y; stB[4*t+2] = fB_.z; stB[4*t+3] = fB_.w; } \
  } else { \
    _Pragma("unroll") \
    for (int t = 0; t < 16; t++){ \
      float4 fA_ = ((const float4*)&xbA[(u-32) * ROWS + 32])[t]; \
      float4 fB_ = ((const float4*)&xbB[(u-32) * ROWS + 32])[t]; \
      stA[64+4*t] = fA_.x; stA[64+4*t+1] = fA_.y; stA[64+4*t+2] = fA_.z; stA[64+4*t+3] = fA_.w; \
      stB[64+4*t] = fB_.x; stB[64+4*t+1] = fB_.y; stB[64+4*t+2] = fB_.z; stB[64+4*t+3] = fB_.w; } \
  } \
  FENCE(); \
}while(0)

// dual merged diagonal, runtime d in {2..5}: reg tables from LDS (A: tabs, B: tabsE
// for even d, shared tabs for odd), lane factors from registers (each lane only ever
// needs its OWN entry -> no LDS), sx masks shared between samples
#define DIAG2(d) do{ \
  const int par_ = (d) & 1; \
  vf2 lpA_ = ((d)==2) ? lA[1] : ((d)==3) ? lA[2] : ((d)==4) ? lA[3] : lA[4]; \
  vf2 lpB_ = ((d)==2) ? lB[1] : ((d)==3) ? lA[2] : ((d)==4) ? lB[3] : lA[4]; \
  vf2 lpnA_ = -lpA_, lpnB_ = -lpB_; \
  const vf2* tA_ = &tabs[(d)-1][0]; \
  const vf2* tB_ = par_ ? tA_ : &tabsE[((d)>>1)-1][0]; \
  const unsigned m_ = par_ ? ( ((u >> 5) & 1u) | ((u & 1u) << 5) ) \
                           : ( (((u >> 1) & 1u) << 5) | ((u & 1u) << 4) \
                             | (((u >> 5) & 1u) << 1) | ((u >> 4) & 1u) ); \
  _Pragma("unroll") \
  for (int w = 0; w < 64; w++){ \
    const int sx_ = __popc((unsigned)w & m_) & 1; \
    vf2 dA_ = tA_[w], dB_ = tB_[w]; \
    { vf2 a_; a_.x = stA[2*w]; a_.y = stA[2*w+1]; \
      vf2 t_ = cmulv(a_, dA_); vf2 r_ = cmulv(t_, sx_ ? lpnA_ : lpA_); \
      stA[2*w] = r_.x; stA[2*w+1] = r_.y; } \
    { vf2 a_; a_.x = stB[2*w]; a_.y = stB[2*w+1]; \
      vf2 t_ = cmulv(a_, dB_); vf2 r_ = cmulv(t_, sx_ ? lpnB_ : lpB_); \
      stB[2*w] = r_.x; stB[2*w+1] = r_.y; } \
  } \
}while(0)

__global__ __attribute__((amdgpu_flat_work_group_size(64,64)))
__attribute__((amdgpu_waves_per_eu(1)))
void qiddm_wave(const float* __restrict__ gx,
                const float* __restrict__ gcw,
                const float* __restrict__ gcb,
                const float* __restrict__ gw1,
                const float* __restrict__ glw,
                const float* __restrict__ glb,
                float* __restrict__ gout)
{
  // TWO samples per wave (stA, stB = 256 VGPRs of state): rounds 1-3 proved wave
  // co-residency never materializes (occupancy pinned ~11%), R4/R5 proved the ~48%
  // non-VALU time is fillable stalls -> fill them with a second in-wave instruction
  // stream.  All weight-only quantities (gate tans, sx masks, odd-d diagonals, conv
  // filters, linear rows, product-state init) are shared between the two samples;
  // states only diverge at the first xr-dependent diagonal (k=4), so k=2..3 run
  // single-stream and stB starts as a copy.  Grid = 1024 blocks -> fully resident.
  // L0 layout: lane u = idx bits 11..6 (wires 0..5), reg w = idx bits 5..0
  // LDS: 2*16896 + 5*512 + 2*512 + 576 = 37952 B -> 4 blocks/CU
  __shared__ vf2 xbA[32 * ROWS];    // sample-A two-phase transpose buffer (16896 B)
  __shared__ vf2 xbB[32 * ROWS];    // sample-B buffer (aliases conv image B)
  __shared__ vf2 tabs[5][64];       // reg-domain diagonal tables, sample A (odd d shared)
  __shared__ vf2 tabsE[2][64];      // reg-domain tables for EVEN d (xr-dependent), sample B
  __shared__ vf2 scsl[72];          // (cos, tan) of theta/2 per (sublayer, wire) -- weights only

  const int u = threadIdx.x;        // lane 0..63
  const int bid = blockIdx.x;
  const int sid0 = bid * 2, sid1 = bid * 2 + 1;

  float xrA[12], xrB[12];           // circuit inputs / expvals (constant-indexed only)

  // ---------- conv 3x3 s2 p1 + bias + GAP, both samples interleaved ----------
  {
    float* imgA = (float*)xbA;      // 4096 B each, wave-private
    float* imgB = (float*)xbB;
#pragma unroll
    for (int i = 0; i < 4; i++){
      float4 qA = ((const float4*)gx)[(size_t)sid0 * 256 + i * 64 + u];
      float4 qB = ((const float4*)gx)[(size_t)sid1 * 256 + i * 64 + u];
      ((float4*)imgA)[i * 64 + u] = qA;
      ((float4*)imgB)[i * 64 + u] = qB;
    }
    FENCE();
    float pA[4][9], pB[4][9];
#pragma unroll
    for (int i = 0; i < 4; i++){
      int pos = u + 64 * i, oi = pos >> 4, oj = pos & 15;
#pragma unroll
      for (int ki = 0; ki < 3; ki++)
#pragma unroll
        for (int kj = 0; kj < 3; kj++){
          int ri = 2*oi - 1 + ki, cj = 2*oj - 1 + kj;
          const bool ok = (ri >= 0 && ri < 32 && cj >= 0 && cj < 32);
          const int ix = ri*32+cj;
          pA[i][ki*3+kj] = ok ? imgA[ix] : 0.0f;
          pB[i][ki*3+kj] = ok ? imgB[ix] : 0.0f;
        }
    }
#pragma unroll
    for (int q = 0; q < 12; q++){
      float aA = 0.0f, aB = 0.0f;
#pragma unroll
      for (int e = 0; e < 9; e++){
        float wv = gcw[q*9+e];                  // uniform -> scalarized, shared A/B
#pragma unroll
        for (int i = 0; i < 4; i++){ aA += pA[i][e] * wv; aB += pB[i][e] * wv; }
      }
#pragma unroll
      for (int off = 32; off; off >>= 1){ aA += __shfl_xor(aA, off); aB += __shfl_xor(aB, off); }
      xrA[q] = gcb[q] + aA * (1.0f/256.0f);
      xrB[q] = gcb[q] + aB * (1.0f/256.0f);
    }
  }

#pragma unroll 1
  for (int n = 0; n < 2; n++){
    const float* W = gw1 + n * 216;

    // ---- RY (cos, tan) table + deferred-cosine product C (weights only -> shared) ----
    float myc = 1.0f;
#pragma unroll
    for (int rep = 0; rep < 2; rep++){
      int e = u + rep * 64;
      if (e < 72){
        float sv, cv; __sincosf(0.5f * W[e*3+1], &sv, &cv);
        vf2 ct; ct.x = cv; ct.y = __fdividef(sv, cv); scsl[e] = ct;
        if (e >= 12) myc *= cv;
      }
    }
#pragma unroll
    for (int off = 32; off; off >>= 1) myc *= __shfl_xor(myc, off);
    const float C2 = myc * myc;                 // wave-uniform probability scale

    // ---- diagonal tables; lane-domain factors kept in REGISTERS (own entry only) ----
    vf2 lA[5], lB[5];                           // compile-time indexed everywhere
#pragma unroll
    for (int d = 1; d <= 5; d++){
      const int par = d & 1;                    // 1 -> applied in L1 (r=1), 0 -> L0 (r=2)
      const int r = par ? 1 : 2;
      {                                         // reg-domain table(s)
        float phA = 0.0f, phB = 0.0f;
#pragma unroll
        for (int lb = 0; lb < 6; lb++){
          int wire = par ? (5 - lb) : (11 - lb);
          const float bit = (float)((u >> lb) & 1) - 0.5f;
          phA += ALPHA(d, wire, xrA) * bit;
          if (!par) phB += ALPHA(d, wire, xrB) * bit;
        }
        int idx_r = par ? (u << 6) : u;
        int y = ((idx_r << r) | (idx_r >> (12 - r))) & 0xFFF;
        int s = __popc(idx_r & y) & 1;          // within-reg CZ parity (geometric, shared)
        float sv, cv; __sincosf(phA, &sv, &cv);
        vf2 eA; eA.x = cv; eA.y = sv; if (s) eA = -eA;
        tabs[d-1][u] = eA;
        if (!par){
          __sincosf(phB, &sv, &cv);
          vf2 eB; eB.x = cv; eB.y = sv; if (s) eB = -eB;
          tabsE[(d>>1)-1][u] = eB;
        }
      }
      {                                         // lane-domain factor -> registers
        float phA = 0.0f, phB = 0.0f;
#pragma unroll
        for (int lb = 0; lb < 6; lb++){
          int wire = par ? (11 - lb) : (5 - lb);
          const float bit = (float)((u >> lb) & 1) - 0.5f;
          phA += ALPHA(d, wire, xrA) * bit;
          if (!par) phB += ALPHA(d, wire, xrB) * bit;
        }
        int idx_l = par ? u : (u << 6);
        int y = ((idx_l << r) | (idx_l >> (12 - r))) & 0xFFF;
        int s = __popc(idx_l & y) & 1;          // within-lane CZ parity (shared)
        float sv, cv; __sincosf(phA, &sv, &cv);
        vf2 eA; eA.x = cv; eA.y = sv; if (s) eA = -eA;
        lA[d-1] = eA;
        if (!par){
          __sincosf(phB, &sv, &cv);
          vf2 eB; eB.x = cv; eB.y = sv; if (s) eB = -eB;
          lB[d-1] = eB;
        } else {
          lB[d-1] = eA;                         // odd d weight-only -> identical
        }
      }
    }
    FENCE();                                    // table writes before circuit reads

    // ---- product-state init in L1 (sublayer 0 closed-form; weights only -> same A/B)
    v128f stA, stB;
    float fl = 1.0f;
#pragma unroll
    for (int lb = 0; lb < 6; lb++){
      vf2 ct = scsl[11 - lb];
      fl *= ((u >> lb) & 1) ? (ct.x * ct.y) : ct.x;
    }
    float qc[6], qs[6];
#pragma unroll
    for (int rb = 0; rb < 6; rb++){
      vf2 ct = scsl[5 - rb]; qc[rb] = ct.x; qs[rb] = ct.x * ct.y;
    }
#pragma unroll
    for (int w = 0; w < 64; w++){
      float Qw =  ((w & 1)  ? qs[0] : qc[0]);
      Qw      *=  ((w & 2)  ? qs[1] : qc[1]);
      Qw      *=  ((w & 4)  ? qs[2] : qc[2]);
      Qw      *=  ((w & 8)  ? qs[3] : qc[3]);
      Qw      *=  ((w & 16) ? qs[4] : qc[4]);
      Qw      *=  ((w & 32) ? qs[5] : qc[5]);
      stA[2*w] = fl * Qw; stA[2*w+1] = 0.0f;
    }

    // ---- k=2,3: DIAG(1) + sublayer-1 first half are xr-INDEPENDENT -> single-stream
    {
      vf2 lp_ = lA[0], lpn_ = -lp_;
      const unsigned m_ = ((u >> 5) & 1u) | ((u & 1u) << 5);   // par=1 coupling
#pragma unroll
      for (int w = 0; w < 64; w++){
        const int sx_ = __popc((unsigned)w & m_) & 1;
        vf2 dph_ = tabs[0][w];
        vf2 a_; a_.x = stA[2*w]; a_.y = stA[2*w+1];
        vf2 t_ = cmulv(a_, dph_);
        vf2 r_ = cmulv(t_, sx_ ? lpn_ : lp_);
        stA[2*w] = r_.x; stA[2*w+1] = r_.y;
      }
    }
    GATES6_1(stA, 1, 1);                        // k=2
    TRANSPOSE_S(stA, xbA);                      // k=3
    GATES6_1(stA, 1, 0);
    stB = stA;                                  // first divergence is DIAG(2) below

    // ---- k=4..11 dual-stream ----
#pragma unroll 1
    for (int k = 4; k < 12; k++){
      const int sl  = k >> 1;
      const int par = ((k + 1) >> 1) & 1;
      if (k & 1) TRANSPOSE2();
      else       DIAG2(sl);
      GATES6_2(sl, par);
    }

    // ---- measurement in L0 (final omega-diagonal dropped); scale by C2 ----
    {
      float PA = 0.f, PB = 0.f;
      float mmA[6] = {0,0,0,0,0,0}, mmB[6] = {0,0,0,0,0,0};
#pragma unroll
      for (int w = 0; w < 64; w++){
        float reA = stA[2*w], imA = stA[2*w+1];
        float reB = stB[2*w], imB = stB[2*w+1];
        float prA = reA*reA + imA*imA;
        float prB = reB*reB + imB*imB;
        PA += prA; PB += prB;
#pragma unroll
        for (int i = 0; i < 6; i++){
          if ((w >> (5 - i)) & 1){ mmA[i] -= prA; mmB[i] -= prB; }
          else                   { mmA[i] += prA; mmB[i] += prB; }
        }
      }
#pragma unroll
      for (int q = 0; q < 12; q++){
        float vA = (q < 6) ? (((u >> (5 - q)) & 1) ? -PA : PA) : mmA[q - 6];
        float vB = (q < 6) ? (((u >> (5 - q)) & 1) ? -PB : PB) : mmB[q - 6];
#pragma unroll
        for (int off = 32; off; off >>= 1){ vA += __shfl_xor(vA, off); vB += __shfl_xor(vB, off); }
        xrA[q] = vA * C2;
        xrB[q] = vB * C2;
      }
    }
  }

  // ---------- final linear: weight rows shared between the two samples ----------
  {
#pragma unroll
    for (int i = 0; i < 16; i++){
      int o = i * 64 + u;
      const float4* wr = (const float4*)(glw + o * 12);   // 48B rows, 16B aligned
      float4 w0 = wr[0], w1 = wr[1], w2 = wr[2];
      float b = glb[o];
      float aA = b, aB = b;
      aA += xrA[0]*w0.x + xrA[1]*w0.y + xrA[2]*w0.z + xrA[3]*w0.w;
      aA += xrA[4]*w1.x + xrA[5]*w1.y + xrA[6]*w1.z + xrA[7]*w1.w;
      aA += xrA[8]*w2.x + xrA[9]*w2.y + xrA[10]*w2.z + xrA[11]*w2.w;
      aB += xrB[0]*w0.x + xrB[1]*w0.y + xrB[2]*w0.z + xrB[3]*w0.w;
      aB += xrB[4]*w1.x + xrB[5]*w1.y + xrB[6]*w1.z + xrB[7]*w1.w;
      aB += xrB[8]*w2.x + xrB[9]*w2.y + xrB[10]*w2.z + xrB[11]*w2.w;
      gout[(size_t)sid0 * 1024 + o] = aA;
      gout[(size_t)sid1 * 1024 + o] = aB;
    }
  }
}

extern "C" void kernel_launch(void* const* d_in, const int* in_sizes, int n_in,
                              void* d_out, int out_size, void* d_ws, size_t ws_size,
                              hipStream_t stream)
{
  (void)n_in; (void)d_ws; (void)ws_size; (void)out_size;
  const float* x  = (const float*)d_in[0];
  const float* cw = (const float*)d_in[1];
  const float* cb = (const float*)d_in[2];
  const float* w1 = (const float*)d_in[3];
  const float* lw = (const float*)d_in[4];
  const float* lb = (const float*)d_in[5];
  float* out = (float*)d_out;
  const int nb = in_sizes[0] / 1024;   // 2048 samples, TWO per wave
  hipLaunchKernelGGL(qiddm_wave, dim3(nb / 2), dim3(64), 0, stream,
                     x, cw, cb, w1, lw, lb, out);
}

// Round 7
// 201.505 us; speedup vs baseline: 1.9396x; 1.9396x over previous
//
#include <hip/hip_runtime.h>

typedef float vf2  __attribute__((ext_vector_type(2)));
typedef float v128f __attribute__((ext_vector_type(128)));

__device__ __forceinline__ vf2 cmulv(vf2 a, vf2 b){
  vf2 br; br.x = -b.y; br.y = b.x;
  return a.x*b + a.y*br;
}

#define ROWS 66   // 32-row transpose buffer, 66 float2/row (64 + 2 pad -> bank stagger)
#define FENCE() asm volatile("" ::: "memory")

// merged-diagonal angle for wire j of diagonal d (wave-uniform); d, j compile-time
#define ALPHA(d, j) (((d) & 1) \
  ? (W[((((d)>>1)*2+1)*12+(j))*3+0] + W[((((d)>>1)*2+0)*12+(j))*3+2]) \
  : (W[((((d)>>1)*2+0)*12+(j))*3+0] + xr[(j)] + W[(((((d)>>1)-1)*2+1)*12+(j))*3+2]))

// 6 RY gates on the reg-domain bits -- TAN-FORM with deferred cosine (R5-verified):
//   true r0 = c*(a - t*b);  true r1 = c*(b + t*a);  c deferred, applied as C^2 on probs
#define GATES6(sl, par) do{ \
  _Pragma("unroll") \
  for (int lb = 0; lb < 6; lb++){ \
    const int wire_ = (par) ? (5 - lb) : (11 - lb); \
    const float t_ = scsl[(sl)*12 + wire_].y; \
    _Pragma("unroll") \
    for (int w0 = 0; w0 < 64; w0++){ \
      if (w0 & (1 << lb)) continue; \
      const int w1 = w0 | (1 << lb); \
      const float ax_ = st[2*w0], ay_ = st[2*w0+1]; \
      const float bx_ = st[2*w1], by_ = st[2*w1+1]; \
      st[2*w0]   = __builtin_fmaf(-t_, bx_, ax_); \
      st[2*w0+1] = __builtin_fmaf(-t_, by_, ay_); \
      st[2*w1]   = __builtin_fmaf( t_, ax_, bx_); \
      st[2*w1+1] = __builtin_fmaf( t_, ay_, by_); \
    } \
  } \
}while(0)

// Two-phase 64x64 lane<->reg transpose through a 32-row LDS buffer (R2/R3-verified,
// passed twice).  Phase A: cross blocks (lanes<32 export regs 32..63 / import the
// half the other lanes exported -> no hazard, no stash); phase B: diagonal blocks.
// All st[] indices compile-time; per-wave in-order LDS pipe gives cross-lane RAW/WAR
// ordering; FENCE() stops compile-time reordering across phases.
#define TRANSPOSE() do{ \
  if (u < 32){ \
    _Pragma("unroll") \
    for (int w = 32; w < 64; w++){ vf2 t_; t_.x = st[2*w]; t_.y = st[2*w+1]; \
      xbuf[(w-32) * ROWS + u] = t_; } \
  } else { \
    _Pragma("unroll") \
    for (int w = 0; w < 32; w++){ vf2 t_; t_.x = st[2*w]; t_.y = st[2*w+1]; \
      xbuf[w * ROWS + u] = t_; } \
  } \
  FENCE(); \
  if (u < 32){ \
    _Pragma("unroll") \
    for (int t = 0; t < 16; t++){ \
      float4 f_ = ((const float4*)&xbuf[u * ROWS + 32])[t]; \
      st[64+4*t] = f_.x; st[64+4*t+1] = f_.y; st[64+4*t+2] = f_.z; st[64+4*t+3] = f_.w; } \
  } else { \
    _Pragma("unroll") \
    for (int t = 0; t < 16; t++){ \
      float4 f_ = ((const float4*)&xbuf[(u-32) * ROWS])[t]; \
      st[4*t] = f_.x; st[4*t+1] = f_.y; st[4*t+2] = f_.z; st[4*t+3] = f_.w; } \
  } \
  FENCE(); \
  if (u < 32){ \
    _Pragma("unroll") \
    for (int w = 0; w < 32; w++){ vf2 t_; t_.x = st[2*w]; t_.y = st[2*w+1]; \
      xbuf[w * ROWS + u] = t_; } \
  } else { \
    _Pragma("unroll") \
    for (int w = 32; w < 64; w++){ vf2 t_; t_.x = st[2*w]; t_.y = st[2*w+1]; \
      xbuf[(w-32) * ROWS + u] = t_; } \
  } \
  FENCE(); \
  if (u < 32){ \
    _Pragma("unroll") \
    for (int t = 0; t < 16; t++){ \
      float4 f_ = ((const float4*)&xbuf[u * ROWS])[t]; \
      st[4*t] = f_.x; st[4*t+1] = f_.y; st[4*t+2] = f_.z; st[4*t+3] = f_.w; } \
  } else { \
    _Pragma("unroll") \
    for (int t = 0; t < 16; t++){ \
      float4 f_ = ((const float4*)&xbuf[(u-32) * ROWS + 32])[t]; \
      st[64+4*t] = f_.x; st[64+4*t+1] = f_.y; st[64+4*t+2] = f_.z; st[64+4*t+3] = f_.w; } \
  } \
  FENCE(); \
}while(0)

// merged diagonal d (runtime): reg part from tabs (LDS), lane part from REGISTERS
// (each lane only ever reads its own ltab entry -> lA[5], compile-time built);
// cross CZ parity via per-lane bitmask + popc
#define DIAG(d, par) do{ \
  vf2 lp_ = (d)==1 ? lA[0] : (d)==2 ? lA[1] : (d)==3 ? lA[2] : (d)==4 ? lA[3] : lA[4]; \
  vf2 lpn_ = -lp_; \
  const unsigned m_ = (par) ? ( ((u >> 5) & 1u) | ((u & 1u) << 5) ) \
                            : ( (((u >> 1) & 1u) << 5) | ((u & 1u) << 4) \
                              | (((u >> 5) & 1u) << 1) | ((u >> 4) & 1u) ); \
  _Pragma("unroll") \
  for (int w = 0; w < 64; w++){ \
    vf2 dph_ = tabs[(d)-1][w]; \
    const int sx_ = __popc((unsigned)w & m_) & 1; \
    vf2 a_; a_.x = st[2*w]; a_.y = st[2*w+1]; \
    vf2 t_ = cmulv(a_, dph_); \
    vf2 r_ = cmulv(t_, sx_ ? lpn_ : lp_); \
    st[2*w] = r_.x; st[2*w+1] = r_.y; \
  } \
}while(0)

__global__ __attribute__((amdgpu_flat_work_group_size(64,64)))
__attribute__((amdgpu_waves_per_eu(1,8)))
void qiddm_wave(const float* __restrict__ gx,
                const float* __restrict__ gcw,
                const float* __restrict__ gcb,
                const float* __restrict__ gw1,
                const float* __restrict__ glw,
                const float* __restrict__ glb,
                float* __restrict__ gout)
{
  // One wave per sample; 4096-amp state in ONE ext_vector (mem2reg-guaranteed regs).
  // L0 layout: lane u = idx bits 11..6 (wires 0..5), reg w = idx bits 5..0 (wires 6..11)
  // L1 layout: lane u = idx bits 5..0,  reg w = idx bits 11..6
  // RESIDENCY EXPERIMENT (the first config where EVERY static limit allows >=2
  // waves/SIMD): LDS = 16896 + 2560 + 576 = 20032 B -> 8 WGs/CU; waves_per_eu(1,8);
  // VGPR ~165 -> 3 waves/SIMD; 64-thread WGs; no spill.  R6's dual-state ILP spilled
  // (256 VGPR cap, 570 MB scratch writes) -- reverted to R5 math (tan-form, 137 us).
  __shared__ vf2 xbuf[32 * ROWS];   // 16896 B two-phase transpose buffer (aliases conv img)
  __shared__ vf2 tabs[5][64];       // reg-domain diagonal tables
  __shared__ vf2 scsl[72];          // (cos, tan) of theta/2 per (sublayer, wire)

  const int u = threadIdx.x;        // lane 0..63
  const int bid = blockIdx.x;

  float xr[12];                     // circuit inputs / expvals (constant-indexed only)

  // ---------- conv 3x3 s2 p1 + bias + GAP ----------
  {
    float* img = (float*)xbuf;      // 4096 B < 16896 B
#pragma unroll
    for (int i = 0; i < 4; i++){
      float4 q4 = ((const float4*)gx)[(size_t)bid * 256 + i * 64 + u];
      ((float4*)img)[i * 64 + u] = q4;
    }
    FENCE();
    float p[4][9];
#pragma unroll
    for (int i = 0; i < 4; i++){
      int pos = u + 64 * i, oi = pos >> 4, oj = pos & 15;
#pragma unroll
      for (int ki = 0; ki < 3; ki++)
#pragma unroll
        for (int kj = 0; kj < 3; kj++){
          int ri = 2*oi - 1 + ki, cj = 2*oj - 1 + kj;
          p[i][ki*3+kj] = (ri >= 0 && ri < 32 && cj >= 0 && cj < 32) ? img[ri*32+cj] : 0.0f;
        }
    }
#pragma unroll
    for (int q = 0; q < 12; q++){
      float a = 0.0f;
#pragma unroll
      for (int e = 0; e < 9; e++){
        float wv = gcw[q*9+e];                  // uniform -> scalarized
#pragma unroll
        for (int i = 0; i < 4; i++) a += p[i][e] * wv;
      }
#pragma unroll
      for (int off = 32; off; off >>= 1) a += __shfl_xor(a, off);
      xr[q] = gcb[q] + a * (1.0f/256.0f);
    }
  }

#pragma unroll 1
  for (int n = 0; n < 2; n++){
    const float* W = gw1 + n * 216;

    // ---- RY (cos, tan) table (72 gates) + deferred-cosine product C = prod c[12..71]
    float myc = 1.0f;
#pragma unroll
    for (int rep = 0; rep < 2; rep++){
      int e = u + rep * 64;
      if (e < 72){
        float sv, cv; __sincosf(0.5f * W[e*3+1], &sv, &cv);
        vf2 ct; ct.x = cv; ct.y = __fdividef(sv, cv); scsl[e] = ct;
        if (e >= 12) myc *= cv;
      }
    }
#pragma unroll
    for (int off = 32; off; off >>= 1) myc *= __shfl_xor(myc, off);
    const float C2 = myc * myc;                 // wave-uniform probability scale

    // ---- diagonal tables: reg-domain -> LDS (tabs), lane-domain -> REGISTERS (lA) ----
    vf2 lA[5];                                  // compile-time indexed in this loop
#pragma unroll
    for (int d = 1; d <= 5; d++){
      const int par = d & 1;                    // 1 -> applied in L1 (r=1), 0 -> L0 (r=2)
      const int r = par ? 1 : 2;
      {
        float ph = 0.0f;
#pragma unroll
        for (int lb = 0; lb < 6; lb++){
          int wire = par ? (5 - lb) : (11 - lb);          // reg-domain wires
          ph += ALPHA(d, wire) * ((float)((u >> lb) & 1) - 0.5f);
        }
        int idx_r = par ? (u << 6) : u;
        int y = ((idx_r << r) | (idx_r >> (12 - r))) & 0xFFF;
        int s = __popc(idx_r & y) & 1;                    // within-reg CZ parity
        float sv, cv; __sincosf(ph, &sv, &cv);
        vf2 e_; e_.x = cv; e_.y = sv; if (s) e_ = -e_;
        tabs[d-1][u] = e_;
      }
      {
        float ph = 0.0f;
#pragma unroll
        for (int lb = 0; lb < 6; lb++){
          int wire = par ? (11 - lb) : (5 - lb);          // lane-domain wires
          ph += ALPHA(d, wire) * ((float)((u >> lb) & 1) - 0.5f);
        }
        int idx_l = par ? u : (u << 6);
        int y = ((idx_l << r) | (idx_l >> (12 - r))) & 0xFFF;
        int s = __popc(idx_l & y) & 1;                    // within-lane CZ parity
        float sv, cv; __sincosf(ph, &sv, &cv);
        vf2 e_; e_.x = cv; e_.y = sv; if (s) e_ = -e_;
        lA[d-1] = e_;                                     // registers, not LDS
      }
    }
    FENCE();                                    // table writes before circuit reads

    // ---- direct product-state init in L1 (sublayer 0 closed-form; s_j = c_j*t_j)
    v128f st;
    float fl = 1.0f;
#pragma unroll
    for (int lb = 0; lb < 6; lb++){
      vf2 ct = scsl[11 - lb];
      fl *= ((u >> lb) & 1) ? (ct.x * ct.y) : ct.x;   // runtime select, constant index
    }
    float qc[6], qs[6];
#pragma unroll
    for (int rb = 0; rb < 6; rb++){
      vf2 ct = scsl[5 - rb]; qc[rb] = ct.x; qs[rb] = ct.x * ct.y;
    }
#pragma unroll
    for (int w = 0; w < 64; w++){               // w compile-time -> selects fold, CSE shares
      float Qw =  ((w & 1)  ? qs[0] : qc[0]);
      Qw      *=  ((w & 2)  ? qs[1] : qc[1]);
      Qw      *=  ((w & 4)  ? qs[2] : qc[2]);
      Qw      *=  ((w & 8)  ? qs[3] : qc[3]);
      Qw      *=  ((w & 16) ? qs[4] : qc[4]);
      Qw      *=  ((w & 32) ? qs[5] : qc[5]);
      st[2*w] = fl * Qw; st[2*w+1] = 0.0f;
    }

    // ---- circuit: 10 remaining half-sublayer steps (k=2..11), measure ----
#pragma unroll 1
    for (int k = 2; k < 12; k++){
      const int sl  = k >> 1;
      const int par = ((k + 1) >> 1) & 1;
      if (k & 1) TRANSPOSE();                   // flip lane/reg domains
      else       DIAG(sl, par);                 // D_sl before the sublayer's 2nd half
      GATES6(sl, par);
    }

    // ---- measurement in L0; computed state = true/C, so p_true = p~ * C2 ----
    {
      float P = 0.f, mm[6] = {0.f,0.f,0.f,0.f,0.f,0.f};  // wires 6..11 (reg bits 5..0)
#pragma unroll
      for (int w = 0; w < 64; w++){
        float re = st[2*w], im = st[2*w+1];
        float pr = re*re + im*im;
        P += pr;
#pragma unroll
        for (int i = 0; i < 6; i++)
          mm[i] += ((w >> (5 - i)) & 1) ? -pr : pr;
      }
#pragma unroll
      for (int q = 0; q < 12; q++){
        float val = (q < 6) ? (((u >> (5 - q)) & 1) ? -P : P)   // wires 0..5 (lane bits)
                            : mm[q - 6];
#pragma unroll
        for (int off = 32; off; off >>= 1) val += __shfl_xor(val, off);
        xr[q] = val * C2;                       // undo deferred cosines (uniform)
      }
    }
  }

  // ---------- final linear ----------
  {
#pragma unroll
    for (int i = 0; i < 16; i++){
      int o = i * 64 + u;
      const float4* wr = (const float4*)(glw + o * 12);   // 48B rows, 16B aligned
      float4 w0 = wr[0], w1 = wr[1], w2 = wr[2];
      float a = glb[o];
      a += xr[0]*w0.x + xr[1]*w0.y + xr[2]*w0.z + xr[3]*w0.w;
      a += xr[4]*w1.x + xr[5]*w1.y + xr[6]*w1.z + xr[7]*w1.w;
      a += xr[8]*w2.x + xr[9]*w2.y + xr[10]*w2.z + xr[11]*w2.w;
      gout[(size_t)bid * 1024 + o] = a;
    }
  }
}

extern "C" void kernel_launch(void* const* d_in, const int* in_sizes, int n_in,
                              void* d_out, int out_size, void* d_ws, size_t ws_size,
                              hipStream_t stream)
{
  (void)n_in; (void)d_ws; (void)ws_size; (void)out_size;
  const float* x  = (const float*)d_in[0];
  const float* cw = (const float*)d_in[1];
  const float* cb = (const float*)d_in[2];
  const float* w1 = (const float*)d_in[3];
  const float* lw = (const float*)d_in[4];
  const float* lb = (const float*)d_in[5];
  float* out = (float*)d_out;
  const int nb = in_sizes[0] / 1024;   // 2048 samples, one wave each
  hipLaunchKernelGGL(qiddm_wave, dim3(nb), dim3(64), 0, stream,
                     x, cw, cb, w1, lw, lb, out);
}

// Round 8
// 171.533 us; speedup vs baseline: 2.2785x; 1.1747x over previous
//
#include <hip/hip_runtime.h>

typedef float vf2  __attribute__((ext_vector_type(2)));

__device__ __forceinline__ vf2 cmulv(vf2 a, vf2 b){
  vf2 br; br.x = -b.y; br.y = b.x;
  return a.x*b + a.y*br;
}

#define ROWS 66   // transpose-buffer row stride in float2 (64 + 2 pad -> bank stagger)
#define FENCE() asm volatile("" ::: "memory")

// merged-diagonal angle for wire j of diagonal d (wave-uniform); d, j compile-time
#define ALPHA(d, j) (((d) & 1) \
  ? (W[((((d)>>1)*2+1)*12+(j))*3+0] + W[((((d)>>1)*2+0)*12+(j))*3+2]) \
  : (W[((((d)>>1)*2+0)*12+(j))*3+0] + xr[(j)] + W[(((((d)>>1)-1)*2+1)*12+(j))*3+2]))

// 6 RY gates on the reg-domain bits -- TAN-FORM (R5) + PACKED FMA (R8):
//   r0 = a - t*b;  r1 = b + t*a   (uniform cosines deferred -> C^2 on probs)
// State is vf2 st[64]: each amp is an aligned VGPR pair after SROA, so the asm
// operands bind directly (R4's marshalling came from extracting out of one v128f).
// Butterfly = 2x v_pk_fma_f32 instead of 4 scalar FMA.
#define GATES6(sl, par) do{ \
  _Pragma("unroll") \
  for (int lb = 0; lb < 6; lb++){ \
    const int wire_ = (par) ? (5 - lb) : (11 - lb); \
    const float t_ = scsl[(sl)*12 + wire_].y; \
    vf2 tp_; tp_.x = t_;  tp_.y = t_; \
    vf2 tn_; tn_.x = -t_; tn_.y = -t_; \
    _Pragma("unroll") \
    for (int w0 = 0; w0 < 64; w0++){ \
      if (w0 & (1 << lb)) continue; \
      const int w1 = w0 | (1 << lb); \
      vf2 a_ = st[w0], b_ = st[w1], r0_, r1_; \
      asm("v_pk_fma_f32 %0, %1, %2, %3" : "=v"(r0_) : "v"(tn_), "v"(b_), "v"(a_)); \
      asm("v_pk_fma_f32 %0, %1, %2, %3" : "=v"(r1_) : "v"(tp_), "v"(a_), "v"(b_)); \
      st[w0] = r0_; st[w1] = r1_; \
    } \
  } \
}while(0)

// swap lane-domain <-> reg-domain through LDS (conflict-free b64 writes / b128 reads);
// single wave -> in-order LDS pipe, no barrier needed  (R5-verified single-phase form;
// the R7 two-phase variant doubles LDS instruction issue via exec-masked halves)
#define TRANSPOSE() do{ \
  _Pragma("unroll") \
  for (int w = 0; w < 64; w++){ \
    xbuf[w * ROWS + u] = st[w]; \
  } \
  FENCE(); \
  _Pragma("unroll") \
  for (int j = 0; j < 32; j++){ \
    float4 f_ = ((const float4*)&xbuf[u * ROWS])[j]; \
    vf2 e0_, e1_; e0_.x = f_.x; e0_.y = f_.y; e1_.x = f_.z; e1_.y = f_.w; \
    st[2*j] = e0_; st[2*j+1] = e1_; \
  } \
  FENCE(); \
}while(0)

// merged diagonal d (runtime): reg part from tabs, lane part from ltab; cross-domain
// CZ parity via per-lane bitmask + popc
#define DIAG(d, par) do{ \
  vf2 lp_ = ltab[(d)-1][u]; \
  vf2 lpn_ = -lp_; \
  const unsigned m_ = (par) ? ( ((u >> 5) & 1u) | ((u & 1u) << 5) ) \
                            : ( (((u >> 1) & 1u) << 5) | ((u & 1u) << 4) \
                              | (((u >> 5) & 1u) << 1) | ((u >> 4) & 1u) ); \
  _Pragma("unroll") \
  for (int w = 0; w < 64; w++){ \
    vf2 dph_ = tabs[(d)-1][w]; \
    const int sx_ = __popc((unsigned)w & m_) & 1; \
    vf2 a_ = st[w]; \
    vf2 t_ = cmulv(a_, dph_); \
    st[w] = cmulv(t_, sx_ ? lpn_ : lp_); \
  } \
}while(0)

__global__ __attribute__((amdgpu_flat_work_group_size(64,64)))
__attribute__((amdgpu_waves_per_eu(1)))
void qiddm_wave(const float* __restrict__ gx,
                const float* __restrict__ gcw,
                const float* __restrict__ gcb,
                const float* __restrict__ gw1,
                const float* __restrict__ glw,
                const float* __restrict__ glb,
                float* __restrict__ gout)
{
  // One wave per sample; 4096-amp state as vf2 st[64] (constant-indexed -> SROA ->
  // 64 aligned VGPR pairs; pk-asm binds pairs directly, no marshalling).
  // L0 layout: lane u = idx bits 11..6 (wires 0..5), reg w = idx bits 5..0 (wires 6..11)
  // L1 layout: lane u = idx bits 5..0,  reg w = idx bits 11..6
  // Residency verdict (R0-R7): pinned ~1 wave/SIMD regardless of LDS/WG/attr; all
  // remaining optimization is per-wave instruction count (R5: -30% ops -> -22% time).
  __shared__ vf2 xbuf[64 * ROWS];   // 33792 B transpose buffer (aliases conv image)
  __shared__ vf2 tabs[5][64];       // reg-domain diagonal tables
  __shared__ vf2 ltab[5][64];       // lane-domain diagonal factors
  __shared__ vf2 scsl[72];          // (cos, tan) of theta/2 per (sublayer, wire)

  const int u = threadIdx.x;        // lane 0..63
  const int bid = blockIdx.x;

  float xr[12];                     // circuit inputs / expvals (constant-indexed only)

  // ---------- conv 3x3 s2 p1 + bias + GAP ----------
  {
    float* img = (float*)xbuf;
#pragma unroll
    for (int i = 0; i < 4; i++){
      float4 q4 = ((const float4*)gx)[(size_t)bid * 256 + i * 64 + u];
      ((float4*)img)[i * 64 + u] = q4;
    }
    FENCE();
    float p[4][9];
#pragma unroll
    for (int i = 0; i < 4; i++){
      int pos = u + 64 * i, oi = pos >> 4, oj = pos & 15;
#pragma unroll
      for (int ki = 0; ki < 3; ki++)
#pragma unroll
        for (int kj = 0; kj < 3; kj++){
          int ri = 2*oi - 1 + ki, cj = 2*oj - 1 + kj;
          p[i][ki*3+kj] = (ri >= 0 && ri < 32 && cj >= 0 && cj < 32) ? img[ri*32+cj] : 0.0f;
        }
    }
#pragma unroll
    for (int q = 0; q < 12; q++){
      float a = 0.0f;
#pragma unroll
      for (int e = 0; e < 9; e++){
        float wv = gcw[q*9+e];                  // uniform -> scalarized
#pragma unroll
        for (int i = 0; i < 4; i++) a += p[i][e] * wv;
      }
#pragma unroll
      for (int off = 32; off; off >>= 1) a += __shfl_xor(a, off);
      xr[q] = gcb[q] + a * (1.0f/256.0f);
    }
  }

#pragma unroll 1
  for (int n = 0; n < 2; n++){
    const float* W = gw1 + n * 216;

    // ---- RY (cos, tan) table (72 gates) + deferred-cosine product C = prod c[12..71]
    float myc = 1.0f;
#pragma unroll
    for (int rep = 0; rep < 2; rep++){
      int e = u + rep * 64;
      if (e < 72){
        float sv, cv; __sincosf(0.5f * W[e*3+1], &sv, &cv);
        vf2 ct; ct.x = cv; ct.y = __fdividef(sv, cv); scsl[e] = ct;
        if (e >= 12) myc *= cv;
      }
    }
#pragma unroll
    for (int off = 32; off; off >>= 1) myc *= __shfl_xor(myc, off);
    const float C2 = myc * myc;                 // wave-uniform probability scale

    // ---- diagonal tables: reg-domain (tabs) and lane-domain (ltab), d unrolled ----
#pragma unroll
    for (int d = 1; d <= 5; d++){
      const int par = d & 1;                    // 1 -> applied in L1 (r=1), 0 -> L0 (r=2)
      const int r = par ? 1 : 2;
      {
        float ph = 0.0f;
#pragma unroll
        for (int lb = 0; lb < 6; lb++){
          int wire = par ? (5 - lb) : (11 - lb);          // reg-domain wires
          ph += ALPHA(d, wire) * ((float)((u >> lb) & 1) - 0.5f);
        }
        int idx_r = par ? (u << 6) : u;
        int y = ((idx_r << r) | (idx_r >> (12 - r))) & 0xFFF;
        int s = __popc(idx_r & y) & 1;                    // within-reg CZ parity
        float sv, cv; __sincosf(ph, &sv, &cv);
        vf2 e_; e_.x = cv; e_.y = sv; if (s) e_ = -e_;
        tabs[d-1][u] = e_;
      }
      {
        float ph = 0.0f;
#pragma unroll
        for (int lb = 0; lb < 6; lb++){
          int wire = par ? (11 - lb) : (5 - lb);          // lane-domain wires
          ph += ALPHA(d, wire) * ((float)((u >> lb) & 1) - 0.5f);
        }
        int idx_l = par ? u : (u << 6);
        int y = ((idx_l << r) | (idx_l >> (12 - r))) & 0xFFF;
        int s = __popc(idx_l & y) & 1;                    // within-lane CZ parity
        float sv, cv; __sincosf(ph, &sv, &cv);
        vf2 e_; e_.x = cv; e_.y = sv; if (s) e_ = -e_;
        ltab[d-1][u] = e_;
      }
    }
    FENCE();                                    // table writes before circuit reads

    // ---- direct product-state init in L1 (sublayer 0 closed-form; s_j = c_j*t_j)
    vf2 st[64];
    float fl = 1.0f;
#pragma unroll
    for (int lb = 0; lb < 6; lb++){
      vf2 ct = scsl[11 - lb];
      fl *= ((u >> lb) & 1) ? (ct.x * ct.y) : ct.x;   // runtime select, constant index
    }
    float qc[6], qs[6];
#pragma unroll
    for (int rb = 0; rb < 6; rb++){
      vf2 ct = scsl[5 - rb]; qc[rb] = ct.x; qs[rb] = ct.x * ct.y;
    }
#pragma unroll
    for (int w = 0; w < 64; w++){               // w compile-time -> selects fold, CSE shares
      float Qw =  ((w & 1)  ? qs[0] : qc[0]);
      Qw      *=  ((w & 2)  ? qs[1] : qc[1]);
      Qw      *=  ((w & 4)  ? qs[2] : qc[2]);
      Qw      *=  ((w & 8)  ? qs[3] : qc[3]);
      Qw      *=  ((w & 16) ? qs[4] : qc[4]);
      Qw      *=  ((w & 32) ? qs[5] : qc[5]);
      vf2 e_; e_.x = fl * Qw; e_.y = 0.0f;
      st[w] = e_;
    }

    // ---- circuit: 10 remaining half-sublayer steps (k=2..11), measure ----
#pragma unroll 1
    for (int k = 2; k < 12; k++){
      const int sl  = k >> 1;
      const int par = ((k + 1) >> 1) & 1;
      if (k & 1) TRANSPOSE();                   // flip lane/reg domains
      else       DIAG(sl, par);                 // D_sl before the sublayer's 2nd half
      GATES6(sl, par);
    }

    // ---- measurement in L0; computed state = true/C, so p_true = p~ * C2 ----
    // half-sum form: mm[i] = P - 2*S_i, S_i = sum of pr over w with bit (5-i) set
    {
      float P = 0.f, S[6] = {0.f,0.f,0.f,0.f,0.f,0.f};   // wires 6..11 (reg bits 5..0)
#pragma unroll
      for (int w = 0; w < 64; w++){
        float re = st[w].x, im = st[w].y;
        float pr = __builtin_fmaf(im, im, re*re);
        P += pr;
#pragma unroll
        for (int i = 0; i < 6; i++)
          if ((w >> (5 - i)) & 1) S[i] += pr;   // compile-time predicate -> 32 adds per i
      }
#pragma unroll
      for (int q = 0; q < 12; q++){
        float val = (q < 6) ? (((u >> (5 - q)) & 1) ? -P : P)   // wires 0..5 (lane bits)
                            : (P - 2.0f * S[q - 6]);
#pragma unroll
        for (int off = 32; off; off >>= 1) val += __shfl_xor(val, off);
        xr[q] = val * C2;                       // undo deferred cosines (uniform)
      }
    }
  }

  // ---------- final linear ----------
  {
#pragma unroll
    for (int i = 0; i < 16; i++){
      int o = i * 64 + u;
      const float4* wr = (const float4*)(glw + o * 12);   // 48B rows, 16B aligned
      float4 w0 = wr[0], w1 = wr[1], w2 = wr[2];
      float a = glb[o];
      a += xr[0]*w0.x + xr[1]*w0.y + xr[2]*w0.z + xr[3]*w0.w;
      a += xr[4]*w1.x + xr[5]*w1.y + xr[6]*w1.z + xr[7]*w1.w;
      a += xr[8]*w2.x + xr[9]*w2.y + xr[10]*w2.z + xr[11]*w2.w;
      gout[(size_t)bid * 1024 + o] = a;
    }
  }
}

extern "C" void kernel_launch(void* const* d_in, const int* in_sizes, int n_in,
                              void* d_out, int out_size, void* d_ws, size_t ws_size,
                              hipStream_t stream)
{
  (void)n_in; (void)d_ws; (void)ws_size; (void)out_size;
  const float* x  = (const float*)d_in[0];
  const float* cw = (const float*)d_in[1];
  const float* cb = (const float*)d_in[2];
  const float* w1 = (const float*)d_in[3];
  const float* lw = (const float*)d_in[4];
  const float* lb = (const float*)d_in[5];
  float* out = (float*)d_out;
  const int nb = in_sizes[0] / 1024;   // 2048 samples, one wave each
  hipLaunchKernelGGL(qiddm_wave, dim3(nb), dim3(64), 0, stream,
                     x, cw, cb, w1, lw, lb, out);
}

// Round 9
// 171.017 us; speedup vs baseline: 2.2854x; 1.0030x over previous
//
#include <hip/hip_runtime.h>

typedef float vf2  __attribute__((ext_vector_type(2)));

#define ROWS 66   // transpose-buffer row stride in float2 (64 + 2 pad -> bank stagger)
#define FENCE() asm volatile("" ::: "memory")

// merged-diagonal angle for wire j of diagonal d (wave-uniform); d, j compile-time
#define ALPHA(d, j) (((d) & 1) \
  ? (W[((((d)>>1)*2+1)*12+(j))*3+0] + W[((((d)>>1)*2+0)*12+(j))*3+2]) \
  : (W[((((d)>>1)*2+0)*12+(j))*3+0] + xr[(j)] + W[(((((d)>>1)-1)*2+1)*12+(j))*3+2]))

// 6 RY gates, tan-form + packed FMA + op_sel broadcast of t straight from the
// (c,t) pair register (no splat movs).  r0 = a - t*b ; r1 = b + t*a.
// op_sel:[1,..] routes ct.hi (=t) into both halves' multiplier; neg_lo/neg_hi
// on src0 gives the -t side.  R8 proved vf2 binds as an aligned VGPR pair.
#define GATES6(sl, par) do{ \
  _Pragma("unroll") \
  for (int lb = 0; lb < 6; lb++){ \
    const int wire_ = (par) ? (5 - lb) : (11 - lb); \
    vf2 ct_ = scsl[(sl)*12 + wire_]; \
    _Pragma("unroll") \
    for (int w0 = 0; w0 < 64; w0++){ \
      if (w0 & (1 << lb)) continue; \
      const int w1 = w0 | (1 << lb); \
      vf2 a_ = st[w0], b_ = st[w1], r0_, r1_; \
      asm("v_pk_fma_f32 %0, %1, %2, %3 op_sel:[1,0,0] op_sel_hi:[1,1,1] neg_lo:[1,0,0] neg_hi:[1,0,0]" \
          : "=v"(r0_) : "v"(ct_), "v"(b_), "v"(a_)); \
      asm("v_pk_fma_f32 %0, %1, %2, %3 op_sel:[1,0,0] op_sel_hi:[1,1,1]" \
          : "=v"(r1_) : "v"(ct_), "v"(a_), "v"(b_)); \
      st[w0] = r0_; st[w1] = r1_; \
    } \
  } \
}while(0)

// swap lane-domain <-> reg-domain through LDS (conflict-free b64 writes / b128 reads);
// single wave -> in-order LDS pipe, no barrier needed (R5/R8-verified single-phase)
#define TRANSPOSE() do{ \
  _Pragma("unroll") \
  for (int w = 0; w < 64; w++){ \
    xbuf[w * ROWS + u] = st[w]; \
  } \
  FENCE(); \
  _Pragma("unroll") \
  for (int j = 0; j < 32; j++){ \
    float4 f_ = ((const float4*)&xbuf[u * ROWS])[j]; \
    vf2 e0_, e1_; e0_.x = f_.x; e0_.y = f_.y; e1_.x = f_.z; e1_.y = f_.w; \
    st[2*j] = e0_; st[2*j+1] = e1_; \
  } \
  FENCE(); \
}while(0)

// merged diagonal d (runtime), fully packed:
//  - reg part: dual-form table (A=dph, B=i*dph) in one float4 -> 1 ds_read_b128/w,
//    complex mul = pk_mul + pk_fma with op_sel (no neg needed)
//  - lane part: 16 sign-variant registers lv[cls] (cls from w-bits {5,4,1,0},
//    compile-time per w; sign folded by XOR on bit 31 at build), second complex
//    mul = pk_mul + pk_fma with op_sel + neg_lo
//  Inner loop: 4 VALU + 1 LDS per amplitude (was ~14 VALU).
#define DIAG(d, par) do{ \
  vf2 lp_ = (d)==1 ? lA[0] : (d)==2 ? lA[1] : (d)==3 ? lA[2] : (d)==4 ? lA[3] : lA[4]; \
  const unsigned m_ = (par) ? ( ((u >> 5) & 1u) | ((u & 1u) << 5) ) \
                            : ( (((u >> 1) & 1u) << 5) | ((u & 1u) << 4) \
                              | (((u >> 5) & 1u) << 1) | ((u >> 4) & 1u) ); \
  vf2 lv[16]; \
  _Pragma("unroll") \
  for (int c = 0; c < 16; c++){ \
    const unsigned cb = (((c >> 3) & 1u) << 5) | (((c >> 2) & 1u) << 4) \
                      | (((c >> 1) & 1u) << 1) | (c & 1u); \
    const unsigned msk = (unsigned)__popc(m_ & cb) << 31;   /* parity bit -> sign bit */ \
    vf2 t_; \
    t_.x = __uint_as_float(__float_as_uint(lp_.x) ^ msk); \
    t_.y = __uint_as_float(__float_as_uint(lp_.y) ^ msk); \
    lv[c] = t_; \
  } \
  _Pragma("unroll") \
  for (int w = 0; w < 64; w++){ \
    float4 dq_ = tabsAB[(d)-1][w]; \
    vf2 dA_; dA_.x = dq_.x; dA_.y = dq_.y; \
    vf2 dB_; dB_.x = dq_.z; dB_.y = dq_.w; \
    const int cls_ = (((w >> 5) & 1) << 3) | (((w >> 4) & 1) << 2) \
                   | (((w >> 1) & 1) << 1) | (w & 1); \
    vf2 a_ = st[w], p1_, r_, p2_, r2_; \
    asm("v_pk_mul_f32 %0, %1, %2 op_sel:[0,0] op_sel_hi:[0,1]" \
        : "=v"(p1_) : "v"(a_), "v"(dA_)); \
    asm("v_pk_fma_f32 %0, %1, %2, %3 op_sel:[1,0,0] op_sel_hi:[1,1,1]" \
        : "=v"(r_) : "v"(a_), "v"(dB_), "v"(p1_)); \
    vf2 lvc_ = lv[cls_]; \
    asm("v_pk_mul_f32 %0, %1, %2 op_sel:[0,0] op_sel_hi:[0,1]" \
        : "=v"(p2_) : "v"(r_), "v"(lvc_)); \
    asm("v_pk_fma_f32 %0, %1, %2, %3 op_sel:[1,1,0] op_sel_hi:[1,0,1] neg_lo:[1,0,0] neg_hi:[0,0,0]" \
        : "=v"(r2_) : "v"(r_), "v"(lvc_), "v"(p2_)); \
    st[w] = r2_; \
  } \
}while(0)

__global__ __attribute__((amdgpu_flat_work_group_size(64,64)))
__attribute__((amdgpu_waves_per_eu(1)))
void qiddm_wave(const float* __restrict__ gx,
                const float* __restrict__ gcw,
                const float* __restrict__ gcb,
                const float* __restrict__ gw1,
                const float* __restrict__ glw,
                const float* __restrict__ glb,
                float* __restrict__ gout)
{
  // One wave per sample; state as vf2 st[64] (SROA -> 64 aligned VGPR pairs).
  // L0 layout: lane u = idx bits 11..6 (wires 0..5), reg w = idx bits 5..0 (wires 6..11)
  // L1 layout: lane u = idx bits 5..0,  reg w = idx bits 11..6
  // Model (R0-R8): residency pinned ~1 wave/SIMD; 46% VALUBusy ~= wave64 VALU-pipe
  // saturation (issue 1 cyc / occupy 2 on SIMD-32) -> time tracks VALU instr count.
  // LDS: 33792 (xbuf) + 5120 (tabsAB) + 576 (scsl) = 39488 B -> keeps 4 blocks/CU.
  __shared__ vf2 xbuf[64 * ROWS];     // transpose buffer (aliases conv image)
  __shared__ float4 tabsAB[5][64];    // reg-domain diagonal, dual form (A=dph, B=i*dph)
  __shared__ vf2 scsl[72];            // (cos, tan) of theta/2 per (sublayer, wire)

  const int u = threadIdx.x;        // lane 0..63
  const int bid = blockIdx.x;

  float xr[12];                     // circuit inputs / expvals (constant-indexed only)

  // ---------- conv 3x3 s2 p1 + bias + GAP ----------
  {
    float* img = (float*)xbuf;
#pragma unroll
    for (int i = 0; i < 4; i++){
      float4 q4 = ((const float4*)gx)[(size_t)bid * 256 + i * 64 + u];
      ((float4*)img)[i * 64 + u] = q4;
    }
    FENCE();
    float p[4][9];
#pragma unroll
    for (int i = 0; i < 4; i++){
      int pos = u + 64 * i, oi = pos >> 4, oj = pos & 15;
#pragma unroll
      for (int ki = 0; ki < 3; ki++)
#pragma unroll
        for (int kj = 0; kj < 3; kj++){
          int ri = 2*oi - 1 + ki, cj = 2*oj - 1 + kj;
          p[i][ki*3+kj] = (ri >= 0 && ri < 32 && cj >= 0 && cj < 32) ? img[ri*32+cj] : 0.0f;
        }
    }
#pragma unroll
    for (int q = 0; q < 12; q++){
      float a = 0.0f;
#pragma unroll
      for (int e = 0; e < 9; e++){
        float wv = gcw[q*9+e];                  // uniform -> scalarized
#pragma unroll
        for (int i = 0; i < 4; i++) a += p[i][e] * wv;
      }
#pragma unroll
      for (int off = 32; off; off >>= 1) a += __shfl_xor(a, off);
      xr[q] = gcb[q] + a * (1.0f/256.0f);
    }
  }

#pragma unroll 1
  for (int n = 0; n < 2; n++){
    const float* W = gw1 + n * 216;

    // ---- RY (cos, tan) table (72 gates) + deferred-cosine product C = prod c[12..71]
    float myc = 1.0f;
#pragma unroll
    for (int rep = 0; rep < 2; rep++){
      int e = u + rep * 64;
      if (e < 72){
        float sv, cv; __sincosf(0.5f * W[e*3+1], &sv, &cv);
        vf2 ct; ct.x = cv; ct.y = __fdividef(sv, cv); scsl[e] = ct;
        if (e >= 12) myc *= cv;
      }
    }
#pragma unroll
    for (int off = 32; off; off >>= 1) myc *= __shfl_xor(myc, off);
    const float C2 = myc * myc;                 // wave-uniform probability scale

    // ---- diagonal tables: reg-domain -> tabsAB (dual form), lane-domain -> lA regs ----
    vf2 lA[5];                                  // compile-time indexed here; select-chain in DIAG
#pragma unroll
    for (int d = 1; d <= 5; d++){
      const int par = d & 1;                    // 1 -> applied in L1 (r=1), 0 -> L0 (r=2)
      const int r = par ? 1 : 2;
      {
        float ph = 0.0f;
#pragma unroll
        for (int lb = 0; lb < 6; lb++){
          int wire = par ? (5 - lb) : (11 - lb);          // reg-domain wires
          ph += ALPHA(d, wire) * ((float)((u >> lb) & 1) - 0.5f);
        }
        int idx_r = par ? (u << 6) : u;
        int y = ((idx_r << r) | (idx_r >> (12 - r))) & 0xFFF;
        int s = __popc(idx_r & y) & 1;                    // within-reg CZ parity
        float sv, cv; __sincosf(ph, &sv, &cv);
        if (s){ sv = -sv; cv = -cv; }
        float4 q_; q_.x = cv; q_.y = sv; q_.z = -sv; q_.w = cv;   // A = dph, B = i*dph
        tabsAB[d-1][u] = q_;
      }
      {
        float ph = 0.0f;
#pragma unroll
        for (int lb = 0; lb < 6; lb++){
          int wire = par ? (11 - lb) : (5 - lb);          // lane-domain wires
          ph += ALPHA(d, wire) * ((float)((u >> lb) & 1) - 0.5f);
        }
        int idx_l = par ? u : (u << 6);
        int y = ((idx_l << r) | (idx_l >> (12 - r))) & 0xFFF;
        int s = __popc(idx_l & y) & 1;                    // within-lane CZ parity
        float sv, cv; __sincosf(ph, &sv, &cv);
        vf2 e_; e_.x = cv; e_.y = sv; if (s) e_ = -e_;
        lA[d-1] = e_;                                     // registers, not LDS
      }
    }
    FENCE();                                    // table writes before circuit reads

    // ---- direct product-state init in L1 (sublayer 0 closed-form; s_j = c_j*t_j)
    vf2 st[64];
    float fl = 1.0f;
#pragma unroll
    for (int lb = 0; lb < 6; lb++){
      vf2 ct = scsl[11 - lb];
      fl *= ((u >> lb) & 1) ? (ct.x * ct.y) : ct.x;   // runtime select, constant index
    }
    float qc[6], qs[6];
#pragma unroll
    for (int rb = 0; rb < 6; rb++){
      vf2 ct = scsl[5 - rb]; qc[rb] = ct.x; qs[rb] = ct.x * ct.y;
    }
#pragma unroll
    for (int w = 0; w < 64; w++){               // w compile-time -> selects fold, CSE shares
      float Qw =  ((w & 1)  ? qs[0] : qc[0]);
      Qw      *=  ((w & 2)  ? qs[1] : qc[1]);
      Qw      *=  ((w & 4)  ? qs[2] : qc[2]);
      Qw      *=  ((w & 8)  ? qs[3] : qc[3]);
      Qw      *=  ((w & 16) ? qs[4] : qc[4]);
      Qw      *=  ((w & 32) ? qs[5] : qc[5]);
      vf2 e_; e_.x = fl * Qw; e_.y = 0.0f;
      st[w] = e_;
    }

    // ---- circuit: 10 remaining half-sublayer steps (k=2..11), measure ----
#pragma unroll 1
    for (int k = 2; k < 12; k++){
      const int sl  = k >> 1;
      const int par = ((k + 1) >> 1) & 1;
      if (k & 1) TRANSPOSE();                   // flip lane/reg domains
      else       DIAG(sl, par);                 // D_sl before the sublayer's 2nd half
      GATES6(sl, par);
    }

    // ---- measurement in L0; packed accumulate: acc += (re^2, im^2) in 1 instr ----
    // half-sum form: mm[i] = P - 2*S_i; final P/S = lo+hi of packed accumulators
    {
      vf2 Pp; Pp.x = 0.f; Pp.y = 0.f;
      vf2 Sp[6];
#pragma unroll
      for (int i = 0; i < 6; i++){ Sp[i].x = 0.f; Sp[i].y = 0.f; }
#pragma unroll
      for (int w = 0; w < 64; w++){
        vf2 s_ = st[w];
        asm("v_pk_fma_f32 %0, %1, %1, %0" : "+v"(Pp) : "v"(s_));
#pragma unroll
        for (int i = 0; i < 6; i++)
          if ((w >> (5 - i)) & 1)
            asm("v_pk_fma_f32 %0, %1, %1, %0" : "+v"(Sp[i]) : "v"(s_));
      }
      float P = Pp.x + Pp.y;
      float S[6];
#pragma unroll
      for (int i = 0; i < 6; i++) S[i] = Sp[i].x + Sp[i].y;
#pragma unroll
      for (int q = 0; q < 12; q++){
        float val = (q < 6) ? (((u >> (5 - q)) & 1) ? -P : P)   // wires 0..5 (lane bits)
                            : (P - 2.0f * S[q - 6]);
#pragma unroll
        for (int off = 32; off; off >>= 1) val += __shfl_xor(val, off);
        xr[q] = val * C2;                       // undo deferred cosines (uniform)
      }
    }
  }

  // ---------- final linear ----------
  {
#pragma unroll
    for (int i = 0; i < 16; i++){
      int o = i * 64 + u;
      const float4* wr = (const float4*)(glw + o * 12);   // 48B rows, 16B aligned
      float4 w0 = wr[0], w1 = wr[1], w2 = wr[2];
      float a = glb[o];
      a += xr[0]*w0.x + xr[1]*w0.y + xr[2]*w0.z + xr[3]*w0.w;
      a += xr[4]*w1.x + xr[5]*w1.y + xr[6]*w1.z + xr[7]*w1.w;
      a += xr[8]*w2.x + xr[9]*w2.y + xr[10]*w2.z + xr[11]*w2.w;
      gout[(size_t)bid * 1024 + o] = a;
    }
  }
}

extern "C" void kernel_launch(void* const* d_in, const int* in_sizes, int n_in,
                              void* d_out, int out_size, void* d_ws, size_t ws_size,
                              hipStream_t stream)
{
  (void)n_in; (void)d_ws; (void)ws_size; (void)out_size;
  const float* x  = (const float*)d_in[0];
  const float* cw = (const float*)d_in[1];
  const float* cb = (const float*)d_in[2];
  const float* w1 = (const float*)d_in[3];
  const float* lw = (const float*)d_in[4];
  const float* lb = (const float*)d_in[5];
  float* out = (float*)d_out;
  const int nb = in_sizes[0] / 1024;   // 2048 samples, one wave each
  hipLaunchKernelGGL(qiddm_wave, dim3(nb), dim3(64), 0, stream,
                     x, cw, cb, w1, lw, lb, out);
}

// Round 10
// 167.957 us; speedup vs baseline: 2.3270x; 1.0182x over previous
//
#include <hip/hip_runtime.h>

typedef float vf2  __attribute__((ext_vector_type(2)));

__device__ __forceinline__ vf2 cmulv(vf2 a, vf2 b){
  vf2 br; br.x = -b.y; br.y = b.x;
  return a.x*b + a.y*br;
}

#define ROWS 66   // transpose-buffer row stride in float2 (64 + 2 pad -> bank stagger)
#define FENCE() asm volatile("" ::: "memory")

// merged-diagonal angle for wire j of diagonal d (wave-uniform); d, j compile-time
#define ALPHA(d, j) (((d) & 1) \
  ? (W[((((d)>>1)*2+1)*12+(j))*3+0] + W[((((d)>>1)*2+0)*12+(j))*3+2]) \
  : (W[((((d)>>1)*2+0)*12+(j))*3+0] + xr[(j)] + W[(((((d)>>1)-1)*2+1)*12+(j))*3+2]))

// Hoist the 6 (c,t) pairs of one GATES6 pass as 3 ds_read_b128 into registers.
// scsl entries [sl*12 + (par?0:6) .. +5]; 48B-aligned -> b128-clean.
// Replaces 6 serialized broadcast-read->wait chains with one overlapped wait.
#define LOADCT(dst, sl, par) do{ \
  const float4* p_ = (const float4*)&scsl[(sl)*12 + ((par)?0:6)]; \
  float4 a_ = p_[0], b_ = p_[1], c_ = p_[2]; \
  dst[0].x=a_.x; dst[0].y=a_.y; dst[1].x=a_.z; dst[1].y=a_.w; \
  dst[2].x=b_.x; dst[2].y=b_.y; dst[3].x=b_.z; dst[3].y=b_.w; \
  dst[4].x=c_.x; dst[4].y=c_.y; dst[5].x=c_.z; dst[5].y=c_.w; \
}while(0)

// 6 RY gates, tan-form + packed FMA, (c,t) pairs pre-hoisted in ct[] registers.
// Stage lb uses ct[5-lb] (compile-time).  op_sel:[1,..] broadcasts t (=pair.hi)
// into both halves; neg on src0 gives -t.  r0 = a - t*b ; r1 = b + t*a.
// (asm form verified correct by R9's pass; R8 proved vf2 binds as VGPR pair)
#define GATES6R(ct) do{ \
  _Pragma("unroll") \
  for (int lb = 0; lb < 6; lb++){ \
    vf2 ct_ = ct[5-lb]; \
    _Pragma("unroll") \
    for (int w0 = 0; w0 < 64; w0++){ \
      if (w0 & (1 << lb)) continue; \
      const int w1 = w0 | (1 << lb); \
      vf2 a_ = st[w0], b_ = st[w1], r0_, r1_; \
      asm("v_pk_fma_f32 %0, %1, %2, %3 op_sel:[1,0,0] op_sel_hi:[1,1,1] neg_lo:[1,0,0] neg_hi:[1,0,0]" \
          : "=v"(r0_) : "v"(ct_), "v"(b_), "v"(a_)); \
      asm("v_pk_fma_f32 %0, %1, %2, %3 op_sel:[1,0,0] op_sel_hi:[1,1,1]" \
          : "=v"(r1_) : "v"(ct_), "v"(a_), "v"(b_)); \
      st[w0] = r0_; st[w1] = r1_; \
    } \
  } \
}while(0)

// swap lane-domain <-> reg-domain through LDS (conflict-free b64 writes / b128 reads);
// single wave -> in-order LDS pipe, no barrier needed (R5/R8-verified single-phase)
#define TRANSPOSE() do{ \
  _Pragma("unroll") \
  for (int w = 0; w < 64; w++){ \
    xbuf[w * ROWS + u] = st[w]; \
  } \
  FENCE(); \
  _Pragma("unroll") \
  for (int j = 0; j < 32; j++){ \
    float4 f_ = ((const float4*)&xbuf[u * ROWS])[j]; \
    vf2 e0_, e1_; e0_.x = f_.x; e0_.y = f_.y; e1_.x = f_.z; e1_.y = f_.w; \
    st[2*j] = e0_; st[2*j+1] = e1_; \
  } \
  FENCE(); \
}while(0)

// merged diagonal d (runtime), par COMPILE-TIME: reg part from tabs, lane part from
// ltab; cross-domain CZ parity via per-lane bitmask + popc  (R8-verified body)
#define DIAG(d, par) do{ \
  vf2 lp_ = ltab[(d)-1][u]; \
  vf2 lpn_ = -lp_; \
  const unsigned m_ = (par) ? ( ((u >> 5) & 1u) | ((u & 1u) << 5) ) \
                            : ( (((u >> 1) & 1u) << 5) | ((u & 1u) << 4) \
                              | (((u >> 5) & 1u) << 1) | ((u >> 4) & 1u) ); \
  _Pragma("unroll") \
  for (int w = 0; w < 64; w++){ \
    vf2 dph_ = tabs[(d)-1][w]; \
    const int sx_ = __popc((unsigned)w & m_) & 1; \
    vf2 a_ = st[w]; \
    vf2 t_ = cmulv(a_, dph_); \
    st[w] = cmulv(t_, sx_ ? lpn_ : lp_); \
  } \
}while(0)

__global__ __attribute__((amdgpu_flat_work_group_size(64,64)))
__attribute__((amdgpu_waves_per_eu(1)))
void qiddm_wave(const float* __restrict__ gx,
                const float* __restrict__ gcw,
                const float* __restrict__ gcb,
                const float* __restrict__ gw1,
                const float* __restrict__ glw,
                const float* __restrict__ glb,
                float* __restrict__ gout)
{
  // One wave per sample; state as vf2 st[64] (SROA -> 64 aligned VGPR pairs).
  // L0 layout: lane u = idx bits 11..6 (wires 0..5), reg w = idx bits 5..0 (wires 6..11)
  // L1 layout: lane u = idx bits 5..0,  reg w = idx bits 11..6
  // R9 finding: removing VALU cycles no longer moves the wall -> stall-bound.
  // This round: sublayer loop with COMPILE-TIME parity + batched (c,t) register
  // hoists (3x b128 instead of 6 serialized broadcast reads per GATES6), second
  // pass's pairs loaded before TRANSPOSE so the wait hides under transpose traffic.
  __shared__ vf2 xbuf[64 * ROWS];   // 33792 B transpose buffer (aliases conv image)
  __shared__ vf2 tabs[5][64];       // reg-domain diagonal tables
  __shared__ vf2 ltab[5][64];       // lane-domain diagonal factors
  __shared__ vf2 scsl[72];          // (cos, tan) of theta/2 per (sublayer, wire)

  const int u = threadIdx.x;        // lane 0..63
  const int bid = blockIdx.x;

  float xr[12];                     // circuit inputs / expvals (constant-indexed only)

  // ---------- conv 3x3 s2 p1 + bias + GAP ----------
  {
    float* img = (float*)xbuf;
#pragma unroll
    for (int i = 0; i < 4; i++){
      float4 q4 = ((const float4*)gx)[(size_t)bid * 256 + i * 64 + u];
      ((float4*)img)[i * 64 + u] = q4;
    }
    FENCE();
    float p[4][9];
#pragma unroll
    for (int i = 0; i < 4; i++){
      int pos = u + 64 * i, oi = pos >> 4, oj = pos & 15;
#pragma unroll
      for (int ki = 0; ki < 3; ki++)
#pragma unroll
        for (int kj = 0; kj < 3; kj++){
          int ri = 2*oi - 1 + ki, cj = 2*oj - 1 + kj;
          p[i][ki*3+kj] = (ri >= 0 && ri < 32 && cj >= 0 && cj < 32) ? img[ri*32+cj] : 0.0f;
        }
    }
#pragma unroll
    for (int q = 0; q < 12; q++){
      float a = 0.0f;
#pragma unroll
      for (int e = 0; e < 9; e++){
        float wv = gcw[q*9+e];                  // uniform -> scalarized
#pragma unroll
        for (int i = 0; i < 4; i++) a += p[i][e] * wv;
      }
#pragma unroll
      for (int off = 32; off; off >>= 1) a += __shfl_xor(a, off);
      xr[q] = gcb[q] + a * (1.0f/256.0f);
    }
  }

#pragma unroll 1
  for (int n = 0; n < 2; n++){
    const float* W = gw1 + n * 216;

    // ---- RY (cos, tan) table (72 gates) + deferred-cosine product C = prod c[12..71]
    float myc = 1.0f;
#pragma unroll
    for (int rep = 0; rep < 2; rep++){
      int e = u + rep * 64;
      if (e < 72){
        float sv, cv; __sincosf(0.5f * W[e*3+1], &sv, &cv);
        vf2 ct; ct.x = cv; ct.y = __fdividef(sv, cv); scsl[e] = ct;
        if (e >= 12) myc *= cv;
      }
    }
#pragma unroll
    for (int off = 32; off; off >>= 1) myc *= __shfl_xor(myc, off);
    const float C2 = myc * myc;                 // wave-uniform probability scale

    // ---- diagonal tables: reg-domain (tabs) and lane-domain (ltab), d unrolled ----
#pragma unroll
    for (int d = 1; d <= 5; d++){
      const int par = d & 1;                    // 1 -> applied in L1 (r=1), 0 -> L0 (r=2)
      const int r = par ? 1 : 2;
      {
        float ph = 0.0f;
#pragma unroll
        for (int lb = 0; lb < 6; lb++){
          int wire = par ? (5 - lb) : (11 - lb);          // reg-domain wires
          ph += ALPHA(d, wire) * ((float)((u >> lb) & 1) - 0.5f);
        }
        int idx_r = par ? (u << 6) : u;
        int y = ((idx_r << r) | (idx_r >> (12 - r))) & 0xFFF;
        int s = __popc(idx_r & y) & 1;                    // within-reg CZ parity
        float sv, cv; __sincosf(ph, &sv, &cv);
        vf2 e_; e_.x = cv; e_.y = sv; if (s) e_ = -e_;
        tabs[d-1][u] = e_;
      }
      {
        float ph = 0.0f;
#pragma unroll
        for (int lb = 0; lb < 6; lb++){
          int wire = par ? (11 - lb) : (5 - lb);          // lane-domain wires
          ph += ALPHA(d, wire) * ((float)((u >> lb) & 1) - 0.5f);
        }
        int idx_l = par ? u : (u << 6);
        int y = ((idx_l << r) | (idx_l >> (12 - r))) & 0xFFF;
        int s = __popc(idx_l & y) & 1;                    // within-lane CZ parity
        float sv, cv; __sincosf(ph, &sv, &cv);
        vf2 e_; e_.x = cv; e_.y = sv; if (s) e_ = -e_;
        ltab[d-1][u] = e_;
      }
    }
    FENCE();                                    // table writes before circuit reads

    // ---- direct product-state init in L1 (sublayer 0 closed-form; s_j = c_j*t_j)
    vf2 st[64];
    float fl = 1.0f;
#pragma unroll
    for (int lb = 0; lb < 6; lb++){
      vf2 ct = scsl[11 - lb];
      fl *= ((u >> lb) & 1) ? (ct.x * ct.y) : ct.x;   // runtime select, constant index
    }
    float qc[6], qs[6];
#pragma unroll
    for (int rb = 0; rb < 6; rb++){
      vf2 ct = scsl[5 - rb]; qc[rb] = ct.x; qs[rb] = ct.x * ct.y;
    }
#pragma unroll
    for (int w = 0; w < 64; w++){               // w compile-time -> selects fold, CSE shares
      float Qw =  ((w & 1)  ? qs[0] : qc[0]);
      Qw      *=  ((w & 2)  ? qs[1] : qc[1]);
      Qw      *=  ((w & 4)  ? qs[2] : qc[2]);
      Qw      *=  ((w & 8)  ? qs[3] : qc[3]);
      Qw      *=  ((w & 16) ? qs[4] : qc[4]);
      Qw      *=  ((w & 32) ? qs[5] : qc[5]);
      vf2 e_; e_.x = fl * Qw; e_.y = 0.0f;
      st[w] = e_;
    }

    // ---- circuit: 5 sublayers (k=2..11 regrouped), compile-time parity per block ----
    // odd sl (1,3,5):  DIAG(sl,1); G6(par=1); TRANSPOSE; G6(par=0)
    // even sl (2,4):   DIAG(sl,0); G6(par=0); TRANSPOSE; G6(par=1)
#pragma unroll 1
    for (int slp = 0; slp < 3; slp++){
      const int sl = 2*slp + 1;                 // odd sublayer
      {
        vf2 ctA[6], ctB[6];
        LOADCT(ctA, sl, 1);
        DIAG(sl, 1);
        GATES6R(ctA);
        LOADCT(ctB, sl, 0);                     // latency hides under transpose traffic
        TRANSPOSE();
        GATES6R(ctB);
      }
      if (slp < 2){                             // even sublayer (uniform branch)
        const int sle = sl + 1;
        vf2 ctA[6], ctB[6];
        LOADCT(ctA, sle, 0);
        DIAG(sle, 0);
        GATES6R(ctA);
        LOADCT(ctB, sle, 1);
        TRANSPOSE();
        GATES6R(ctB);
      }
    }

    // ---- measurement in L0; computed state = true/C, so p_true = p~ * C2 ----
    // half-sum form: mm[i] = P - 2*S_i, S_i = sum of pr over w with bit (5-i) set
    {
      float P = 0.f, S[6] = {0.f,0.f,0.f,0.f,0.f,0.f};   // wires 6..11 (reg bits 5..0)
#pragma unroll
      for (int w = 0; w < 64; w++){
        float re = st[w].x, im = st[w].y;
        float pr = __builtin_fmaf(im, im, re*re);
        P += pr;
#pragma unroll
        for (int i = 0; i < 6; i++)
          if ((w >> (5 - i)) & 1) S[i] += pr;   // compile-time predicate -> 32 adds per i
      }
#pragma unroll
      for (int q = 0; q < 12; q++){
        float val = (q < 6) ? (((u >> (5 - q)) & 1) ? -P : P)   // wires 0..5 (lane bits)
                            : (P - 2.0f * S[q - 6]);
#pragma unroll
        for (int off = 32; off; off >>= 1) val += __shfl_xor(val, off);
        xr[q] = val * C2;                       // undo deferred cosines (uniform)
      }
    }
  }

  // ---------- final linear ----------
  {
#pragma unroll
    for (int i = 0; i < 16; i++){
      int o = i * 64 + u;
      const float4* wr = (const float4*)(glw + o * 12);   // 48B rows, 16B aligned
      float4 w0 = wr[0], w1 = wr[1], w2 = wr[2];
      float a = glb[o];
      a += xr[0]*w0.x + xr[1]*w0.y + xr[2]*w0.z + xr[3]*w0.w;
      a += xr[4]*w1.x + xr[5]*w1.y + xr[6]*w1.z + xr[7]*w1.w;
      a += xr[8]*w2.x + xr[9]*w2.y + xr[10]*w2.z + xr[11]*w2.w;
      gout[(size_t)bid * 1024 + o] = a;
    }
  }
}

extern "C" void kernel_launch(void* const* d_in, const int* in_sizes, int n_in,
                              void* d_out, int out_size, void* d_ws, size_t ws_size,
                              hipStream_t stream)
{
  (void)n_in; (void)d_ws; (void)ws_size; (void)out_size;
  const float* x  = (const float*)d_in[0];
  const float* cw = (const float*)d_in[1];
  const float* cb = (const float*)d_in[2];
  const float* w1 = (const float*)d_in[3];
  const float* lw = (const float*)d_in[4];
  const float* lb = (const float*)d_in[5];
  float* out = (float*)d_out;
  const int nb = in_sizes[0] / 1024;   // 2048 samples, one wave each
  hipLaunchKernelGGL(qiddm_wave, dim3(nb), dim3(64), 0, stream,
                     x, cw, cb, w1, lw, lb, out);
}